// Round 1
// baseline (418.814 us; speedup 1.0000x reference)
//
#include <hip/hip_runtime.h>
#include <math.h>

#define Bn 4
#define Qn 300
#define WL 8
#define Hh 64
#define Ww 64
#define Dd 256
#define Mm 4

// ---------------- reduction helpers ----------------
__device__ __forceinline__ float wave_reduce(float v) {
#pragma unroll
    for (int off = 32; off > 0; off >>= 1) v += __shfl_down(v, off, 64);
    return v;
}

// 256-thread block reduce; lds must have >=4 floats
__device__ __forceinline__ float block_reduce256(float v, float* lds) {
    v = wave_reduce(v);
    int lane = threadIdx.x & 63, wv = threadIdx.x >> 6;
    if (lane == 0) lds[wv] = v;
    __syncthreads();
    float r = lds[0] + lds[1] + lds[2] + lds[3];
    __syncthreads();
    return r;
}

// ---------------- kernel 1: LN1(q) + ref = sigmoid(qn @ w_ref + b_ref) ----------------
__global__ void __launch_bounds__(256) k_ln1(const float* __restrict__ q,
                                             const float* __restrict__ g1,
                                             const float* __restrict__ b1,
                                             const float* __restrict__ w_ref,
                                             const float* __restrict__ b_ref,
                                             float* __restrict__ qn,
                                             float* __restrict__ refo) {
    __shared__ float lds[4];
    int bq = blockIdx.x, d = threadIdx.x;
    float x = q[bq * Dd + d];
    float m = block_reduce256(x, lds) * (1.f / Dd);
    float dx = x - m;
    float v = block_reduce256(dx * dx, lds) * (1.f / Dd);
    float y = dx * rsqrtf(v + 1e-5f) * g1[d] + b1[d];
    qn[bq * Dd + d] = y;
    float s0 = block_reduce256(y * w_ref[d * 2 + 0], lds);
    float s1 = block_reduce256(y * w_ref[d * 2 + 1], lds);
    if (d == 0) {
        refo[bq * 2 + 0] = 1.f / (1.f + expf(-(s0 + b_ref[0])));
        refo[bq * 2 + 1] = 1.f / (1.f + expf(-(s1 + b_ref[1])));
    }
}

// ---------------- kernel 2: per (b,q,wl) sampling-point parameters ----------------
// prm record per (b,q,wl,m): [wgt, alpha, wx, wy, t0, t1, x0, x1, y0, y1, 0, 0]
__global__ void __launch_bounds__(256) k_pts(const float* __restrict__ qn,
                                             const float* __restrict__ refo,
                                             const float* __restrict__ dsec,
                                             const float* __restrict__ w_rel,
                                             const float* __restrict__ b_rel,
                                             const float* __restrict__ w_delta,
                                             const float* __restrict__ b_delta,
                                             const float* __restrict__ w_alpha,
                                             const float* __restrict__ b_alpha,
                                             float* __restrict__ prm) {
    __shared__ float pe[64];
    __shared__ float psi[512];
    __shared__ float red[64];   // 4 waves x 16 outputs
    __shared__ float res[16];
    __shared__ float wgt[4];
    int bi = blockIdx.x;          // bq*8 + wl
    int bq = bi >> 3, wl = bi & 7;
    int t = threadIdx.x;
    float ds = dsec[bi];
    if (t < 32) {
        float f = expf(-logf(10000.f) * (float)t * (1.f / 32.f));
        float a = ds * f;
        pe[t] = sinf(a);
        pe[t + 32] = cosf(a);
    }
    psi[t] = qn[bq * Dd + t];
    __syncthreads();
    float rel = b_rel[t];
#pragma unroll
    for (int k = 0; k < 64; k++) rel += pe[k] * w_rel[k * Dd + t];
    psi[256 + t] = rel;
    __syncthreads();
    float p0 = psi[t], p1 = psi[t + 256];
    float part[16];
#pragma unroll
    for (int j = 0; j < 12; j++)
        part[j] = p0 * w_delta[t * 12 + j] + p1 * w_delta[(t + 256) * 12 + j];
#pragma unroll
    for (int j = 0; j < 4; j++)
        part[12 + j] = p0 * w_alpha[t * 4 + j] + p1 * w_alpha[(t + 256) * 4 + j];
    int lane = t & 63, wv = t >> 6;
#pragma unroll
    for (int j = 0; j < 16; j++) {
        float s = wave_reduce(part[j]);
        if (lane == 0) red[wv * 16 + j] = s;
    }
    __syncthreads();
    if (t < 16) {
        float s = red[t] + red[16 + t] + red[32 + t] + red[48 + t];
        s += (t < 12) ? b_delta[t] : b_alpha[t - 12];
        res[t] = s;
    }
    __syncthreads();
    if (t == 0) {
        // softmax over M; the -lam_sp*|dsec| shift is constant across M -> drops out
        float mx = fmaxf(fmaxf(res[12], res[13]), fmaxf(res[14], res[15]));
        float e0 = expf(res[12] - mx), e1 = expf(res[13] - mx);
        float e2 = expf(res[14] - mx), e3 = expf(res[15] - mx);
        float inv = 1.f / (e0 + e1 + e2 + e3);
        wgt[0] = e0 * inv; wgt[1] = e1 * inv; wgt[2] = e2 * inv; wgt[3] = e3 * inv;
    }
    __syncthreads();
    if (t < 4) {
        float refx = refo[bq * 2 + 0], refy = refo[bq * 2 + 1];
        float cx = fminf(fmaxf(refx + tanhf(res[t * 3 + 0]), 0.f), 1.f);
        float cy = fminf(fmaxf(refy + tanhf(res[t * 3 + 1]), 0.f), 1.f);
        float tgt = (float)wl + tanhf(res[t * 3 + 2]);
        float t0f = fminf(fmaxf(floorf(tgt), 0.f), (float)(WL - 1));
        float t1f = fminf(t0f + 1.f, (float)(WL - 1));
        float alpha = tgt - t0f;
        float px = cx * (float)Ww - 0.5f, py = cy * (float)Hh - 0.5f;
        float fx = floorf(px), fy = floorf(py);
        float wx = px - fx, wy = py - fy;
        float x0 = fminf(fmaxf(fx, 0.f), (float)(Ww - 1));
        float x1 = fminf(fmaxf(fx + 1.f, 0.f), (float)(Ww - 1));
        float y0 = fminf(fmaxf(fy, 0.f), (float)(Hh - 1));
        float y1 = fminf(fmaxf(fy + 1.f, 0.f), (float)(Hh - 1));
        float* o = prm + (size_t)(bi * 4 + t) * 12;
        o[0] = wgt[t]; o[1] = alpha; o[2] = wx; o[3] = wy;
        o[4] = t0f; o[5] = t1f; o[6] = x0; o[7] = x1; o[8] = y0; o[9] = y1;
        o[10] = 0.f; o[11] = 0.f;
    }
}

// ---------------- kernel 3: trilinear gather + weighted aggregation ----------------
__global__ void __launch_bounds__(256) k_sample(const float* __restrict__ feats,
                                                const unsigned char* __restrict__ mask,
                                                const float* __restrict__ prm,
                                                float* __restrict__ agg) {
    __shared__ float P[32 * 12];
    int bq = blockIdx.x, d = threadIdx.x;
    int b = bq / Qn;
    for (int i = d; i < 32 * 12; i += 256) P[i] = prm[(size_t)bq * (32 * 12) + i];
    __syncthreads();
    float acc = 0.f;
    for (int p = 0; p < 32; p++) {
        const float* pp = &P[p * 12];
        float wgt = pp[0], alpha = pp[1], wx = pp[2], wy = pp[3];
        int t0 = (int)pp[4], t1 = (int)pp[5];
        int x0 = (int)pp[6], x1 = (int)pp[7];
        int y0 = (int)pp[8], y1 = (int)pp[9];
        float w00 = (1.f - wy) * (1.f - wx), w01 = (1.f - wy) * wx;
        float w10 = wy * (1.f - wx), w11 = wy * wx;
        float wt0 = wgt * (1.f - alpha), wt1 = wgt * alpha;
#pragma unroll
        for (int s = 0; s < 2; s++) {
            int tt = s ? t1 : t0;
            float wts = s ? wt1 : wt0;
            int base = (b * WL + tt) * Hh;
            int i00 = (base + y0) * Ww + x0;
            int i01 = (base + y0) * Ww + x1;
            int i10 = (base + y1) * Ww + x0;
            int i11 = (base + y1) * Ww + x1;
            float m00 = mask[i00] ? 0.f : 1.f;
            float m01 = mask[i01] ? 0.f : 1.f;
            float m10 = mask[i10] ? 0.f : 1.f;
            float m11 = mask[i11] ? 0.f : 1.f;
            float v = w00 * m00 * feats[(size_t)i00 * Dd + d]
                    + w01 * m01 * feats[(size_t)i01 * Dd + d]
                    + w10 * m10 * feats[(size_t)i10 * Dd + d]
                    + w11 * m11 * feats[(size_t)i11 * Dd + d];
            acc += wts * v;
        }
    }
    agg[(size_t)bq * Dd + d] = acc;
}

// ---------------- kernel 4: proj + residual + LN2 + FFN (+residual) ----------------
// 4 rows per block for weight reuse
__global__ void __launch_bounds__(256) k_out(const float* __restrict__ q,
                                             const float* __restrict__ agg,
                                             const float* __restrict__ w_proj,
                                             const float* __restrict__ b_proj,
                                             const float* __restrict__ g2,
                                             const float* __restrict__ b2,
                                             const float* __restrict__ w_ffn1,
                                             const float* __restrict__ b_ffn1,
                                             const float* __restrict__ w_ffn2,
                                             const float* __restrict__ b_ffn2,
                                             float* __restrict__ out) {
    __shared__ float sA[4][256];
    __shared__ float sO[4][256];
    __shared__ float sH[4][256];
    __shared__ float sF[4][1024];
    __shared__ float lds[4];
    int g = blockIdx.x, d = threadIdx.x;
    int row0 = g * 4;
#pragma unroll
    for (int r = 0; r < 4; r++) sA[r][d] = agg[(size_t)(row0 + r) * Dd + d];
    __syncthreads();
    // proj
    float acc[4] = {0.f, 0.f, 0.f, 0.f};
    for (int k = 0; k < 256; k++) {
        float wv = w_proj[k * Dd + d];
#pragma unroll
        for (int r = 0; r < 4; r++) acc[r] += sA[r][k] * wv;
    }
    float bp = b_proj[d];
#pragma unroll
    for (int r = 0; r < 4; r++)
        sO[r][d] = q[(size_t)(row0 + r) * Dd + d] + acc[r] + bp;
    __syncthreads();
    // LN2
    float gg = g2[d], bb = b2[d];
    for (int r = 0; r < 4; r++) {
        float x = sO[r][d];
        float m = block_reduce256(x, lds) * (1.f / 256.f);
        float dx = x - m;
        float v = block_reduce256(dx * dx, lds) * (1.f / 256.f);
        sH[r][d] = dx * rsqrtf(v + 1e-5f) * gg + bb;
    }
    __syncthreads();
    // FFN1 + exact GELU
    float a1[4][4];
#pragma unroll
    for (int r = 0; r < 4; r++)
#pragma unroll
        for (int jj = 0; jj < 4; jj++) a1[r][jj] = 0.f;
    for (int k = 0; k < 256; k++) {
        float w0 = w_ffn1[k * 1024 + d];
        float w1 = w_ffn1[k * 1024 + d + 256];
        float w2 = w_ffn1[k * 1024 + d + 512];
        float w3 = w_ffn1[k * 1024 + d + 768];
#pragma unroll
        for (int r = 0; r < 4; r++) {
            float h = sH[r][k];
            a1[r][0] += h * w0; a1[r][1] += h * w1;
            a1[r][2] += h * w2; a1[r][3] += h * w3;
        }
    }
#pragma unroll
    for (int jj = 0; jj < 4; jj++) {
        float bf = b_ffn1[d + 256 * jj];
#pragma unroll
        for (int r = 0; r < 4; r++) {
            float x = a1[r][jj] + bf;
            sF[r][d + 256 * jj] = 0.5f * x * (1.f + erff(x * 0.70710678118654752f));
        }
    }
    __syncthreads();
    // FFN2 + residual
    float a2[4] = {0.f, 0.f, 0.f, 0.f};
    for (int k = 0; k < 1024; k++) {
        float wv = w_ffn2[k * Dd + d];
#pragma unroll
        for (int r = 0; r < 4; r++) a2[r] += sF[r][k] * wv;
    }
    float bf2 = b_ffn2[d];
#pragma unroll
    for (int r = 0; r < 4; r++)
        out[(size_t)(row0 + r) * Dd + d] = sO[r][d] + a2[r] + bf2;
}

// ---------------- launcher ----------------
extern "C" void kernel_launch(void* const* d_in, const int* in_sizes, int n_in,
                              void* d_out, int out_size, void* d_ws, size_t ws_size,
                              hipStream_t stream) {
    const float* q        = (const float*)d_in[0];
    const float* kv_feats = (const float*)d_in[1];
    const unsigned char* kv_mask = (const unsigned char*)d_in[2];
    const float* delta_sec= (const float*)d_in[3];
    const float* w_ref    = (const float*)d_in[4];
    const float* b_ref    = (const float*)d_in[5];
    const float* w_delta  = (const float*)d_in[6];
    const float* b_delta  = (const float*)d_in[7];
    const float* w_alpha  = (const float*)d_in[8];
    const float* b_alpha  = (const float*)d_in[9];
    // d_in[10] = lam: softmax shift-invariance makes it a no-op
    const float* w_proj   = (const float*)d_in[11];
    const float* b_proj   = (const float*)d_in[12];
    const float* ln1_g    = (const float*)d_in[13];
    const float* ln1_b    = (const float*)d_in[14];
    const float* ln2_g    = (const float*)d_in[15];
    const float* ln2_b    = (const float*)d_in[16];
    const float* w_ffn1   = (const float*)d_in[17];
    const float* b_ffn1   = (const float*)d_in[18];
    const float* w_ffn2   = (const float*)d_in[19];
    const float* b_ffn2   = (const float*)d_in[20];
    const float* w_rel    = (const float*)d_in[21];
    const float* b_rel    = (const float*)d_in[22];
    float* out = (float*)d_out;

    float* ws   = (float*)d_ws;
    float* qn   = ws;                     // 1200*256 = 307200
    float* refo = ws + 307200;            // 1200*2   = 2400
    float* prm  = ws + 309600;            // 9600*4*12 = 460800
    float* agg  = ws + 770400;            // 1200*256 = 307200
    // total 1,077,600 floats = 4.31 MB

    const int BQ = Bn * Qn;               // 1200
    k_ln1<<<dim3(BQ), dim3(256), 0, stream>>>(q, ln1_g, ln1_b, w_ref, b_ref, qn, refo);
    k_pts<<<dim3(BQ * WL), dim3(256), 0, stream>>>(qn, refo, delta_sec, w_rel, b_rel,
                                                   w_delta, b_delta, w_alpha, b_alpha, prm);
    k_sample<<<dim3(BQ), dim3(256), 0, stream>>>(kv_feats, kv_mask, prm, agg);
    k_out<<<dim3(BQ / 4), dim3(256), 0, stream>>>(q, agg, w_proj, b_proj, ln2_g, ln2_b,
                                                  w_ffn1, b_ffn1, w_ffn2, b_ffn2, out);
}

// Round 2
// 347.666 us; speedup vs baseline: 1.2046x; 1.2046x over previous
//
#include <hip/hip_runtime.h>
#include <math.h>

#define Bn 4
#define Qn 300
#define WL 8
#define Hh 64
#define Ww 64
#define Dd 256
#define Mm 4

// ---------------- reduction helpers ----------------
__device__ __forceinline__ float wave_reduce(float v) {
#pragma unroll
    for (int off = 32; off > 0; off >>= 1) v += __shfl_down(v, off, 64);
    return v;
}

// 256-thread block reduce; lds must have >=4 floats
__device__ __forceinline__ float block_reduce256(float v, float* lds) {
    v = wave_reduce(v);
    int lane = threadIdx.x & 63, wv = threadIdx.x >> 6;
    if (lane == 0) lds[wv] = v;
    __syncthreads();
    float r = lds[0] + lds[1] + lds[2] + lds[3];
    __syncthreads();
    return r;
}

// ---------------- kernel 1 (merged LN1 + point parameters) ----------------
// one block per (b,q); 256 threads
// prm record per (b,q,wl,m): [wgt, alpha, wx, wy, t0, t1, x0, x1, y0, y1, 0, 0]
__global__ void __launch_bounds__(256) k_pts(const float* __restrict__ q,
                                             const float* __restrict__ g1,
                                             const float* __restrict__ b1,
                                             const float* __restrict__ w_ref,
                                             const float* __restrict__ b_ref,
                                             const float* __restrict__ dsec,
                                             const float* __restrict__ w_rel,
                                             const float* __restrict__ b_rel,
                                             const float* __restrict__ w_delta,
                                             const float* __restrict__ b_delta,
                                             const float* __restrict__ w_alpha,
                                             const float* __restrict__ b_alpha,
                                             float* __restrict__ prm) {
    __shared__ float lds[4];
    __shared__ float sref[2];
    __shared__ float sqn[256];
    __shared__ float pe[8][64];
    __shared__ float rel[8][260];     // +4 pad: conflict-free b128 rows
    __shared__ float WcT[16 * 516];   // WcT[j][k], row stride 516 (pad 4)
    __shared__ float res[8][16];

    int bq = blockIdx.x, t = threadIdx.x;

    // ---- LN1 ----
    float x = q[bq * Dd + t];
    float m = block_reduce256(x, lds) * (1.f / Dd);
    float dx = x - m;
    float v = block_reduce256(dx * dx, lds) * (1.f / Dd);
    float y = dx * rsqrtf(v + 1e-5f) * g1[t] + b1[t];
    sqn[t] = y;

    // ---- ref = sigmoid(qn @ w_ref + b_ref) ----
    float s0 = block_reduce256(y * w_ref[t * 2 + 0], lds);
    float s1 = block_reduce256(y * w_ref[t * 2 + 1], lds);
    if (t == 0) {
        sref[0] = 1.f / (1.f + expf(-(s0 + b_ref[0])));
        sref[1] = 1.f / (1.f + expf(-(s1 + b_ref[1])));
    }

    // ---- sinusoidal PE for all 8 windows ----
    {
        int wl = t >> 5, i = t & 31;
        float f = expf(-logf(10000.f) * (float)i * (1.f / 32.f));
        float a = dsec[bq * WL + wl] * f;
        pe[wl][i] = sinf(a);
        pe[wl][i + 32] = cosf(a);
    }

    // ---- stage combined delta/alpha weights into LDS (transposed, padded) ----
    for (int u = t; u < 512 * 16; u += 256) {
        int k = u >> 4, jj = u & 15;
        float w = (jj < 12) ? w_delta[k * 12 + jj] : w_alpha[k * 4 + (jj - 12)];
        WcT[jj * 516 + k] = w;
    }

    // ---- w_rel column t in registers (reused across 8 windows) ----
    float wr[64];
#pragma unroll
    for (int k = 0; k < 64; k++) wr[k] = w_rel[k * Dd + t];
    __syncthreads();

    // ---- rel_feat per window ----
    float brl = b_rel[t];
    for (int wl = 0; wl < WL; wl++) {
        float r = brl;
#pragma unroll
        for (int k = 0; k < 64; k++) r += pe[wl][k] * wr[k];
        rel[wl][t] = r;
    }
    __syncthreads();

    // ---- 16 dot products per window: psi = [qn, rel_wl] (512) x WcT col ----
    if (t < 128) {
        int wl = t >> 4, jj = t & 15;
        const float4* wrow = (const float4*)&WcT[jj * 516];
        const float4* qrow = (const float4*)sqn;
        const float4* rrow = (const float4*)&rel[wl][0];
        float s = 0.f;
#pragma unroll 8
        for (int k4 = 0; k4 < 64; k4++) {
            float4 a = qrow[k4], w = wrow[k4];
            s += a.x * w.x + a.y * w.y + a.z * w.z + a.w * w.w;
        }
#pragma unroll 8
        for (int k4 = 0; k4 < 64; k4++) {
            float4 a = rrow[k4], w = wrow[64 + k4];
            s += a.x * w.x + a.y * w.y + a.z * w.z + a.w * w.w;
        }
        s += (jj < 12) ? b_delta[jj] : b_alpha[jj - 12];
        res[wl][jj] = s;
    }
    __syncthreads();

    // ---- softmax weights + coords + trilinear params ----
    if (t < 32) {
        int wl = t >> 2, mm = t & 3;
        float l0 = res[wl][12], l1 = res[wl][13], l2 = res[wl][14], l3 = res[wl][15];
        float mx = fmaxf(fmaxf(l0, l1), fmaxf(l2, l3));
        float inv = 1.f / (expf(l0 - mx) + expf(l1 - mx) + expf(l2 - mx) + expf(l3 - mx));
        // -lam_sp*|dsec| shift is constant across M -> drops out of softmax
        float wgt = expf(res[wl][12 + mm] - mx) * inv;

        float cx = fminf(fmaxf(sref[0] + tanhf(res[wl][mm * 3 + 0]), 0.f), 1.f);
        float cy = fminf(fmaxf(sref[1] + tanhf(res[wl][mm * 3 + 1]), 0.f), 1.f);
        float tgt = (float)wl + tanhf(res[wl][mm * 3 + 2]);
        float t0f = fminf(fmaxf(floorf(tgt), 0.f), (float)(WL - 1));
        float t1f = fminf(t0f + 1.f, (float)(WL - 1));
        float alpha = tgt - t0f;
        float px = cx * (float)Ww - 0.5f, py = cy * (float)Hh - 0.5f;
        float fx = floorf(px), fy = floorf(py);
        float wx = px - fx, wy = py - fy;
        float x0 = fminf(fmaxf(fx, 0.f), (float)(Ww - 1));
        float x1 = fminf(fmaxf(fx + 1.f, 0.f), (float)(Ww - 1));
        float y0 = fminf(fmaxf(fy, 0.f), (float)(Hh - 1));
        float y1 = fminf(fmaxf(fy + 1.f, 0.f), (float)(Hh - 1));
        float* o = prm + (size_t)(bq * 32 + t) * 12;
        o[0] = wgt; o[1] = alpha; o[2] = wx; o[3] = wy;
        o[4] = t0f; o[5] = t1f; o[6] = x0; o[7] = x1; o[8] = y0; o[9] = y1;
        o[10] = 0.f; o[11] = 0.f;
    }
}

// ---------------- kernel 2: trilinear gather + weighted aggregation ----------------
// one block per (b,q); wave j owns points 8j..8j+7; lane l owns channels 4l..4l+3
__global__ void __launch_bounds__(256) k_sample(const float* __restrict__ feats,
                                                const unsigned char* __restrict__ mask,
                                                const float* __restrict__ prm,
                                                float* __restrict__ agg) {
    __shared__ float P[32 * 12];
    __shared__ float part[4][256];
    int bq = blockIdx.x, t = threadIdx.x;
    int b = bq / Qn;
    int l = t & 63, j = t >> 6;
    for (int i = t; i < 32 * 12; i += 256) P[i] = prm[(size_t)bq * (32 * 12) + i];
    __syncthreads();
    const float4* f4 = (const float4*)feats;
    float4 acc = {0.f, 0.f, 0.f, 0.f};
#pragma unroll 2
    for (int p8 = 0; p8 < 8; p8++) {
        const float* pp = &P[(j * 8 + p8) * 12];
        float wgt = pp[0], alpha = pp[1], wx = pp[2], wy = pp[3];
        int t0 = (int)pp[4], t1 = (int)pp[5];
        int x0 = (int)pp[6], x1 = (int)pp[7];
        int y0 = (int)pp[8], y1 = (int)pp[9];
        float w00 = (1.f - wy) * (1.f - wx), w01 = (1.f - wy) * wx;
        float w10 = wy * (1.f - wx), w11 = wy * wx;
        float wt0 = wgt * (1.f - alpha), wt1 = wgt * alpha;
#pragma unroll
        for (int s = 0; s < 2; s++) {
            int tt = s ? t1 : t0;
            float wts = s ? wt1 : wt0;
            int base = (b * WL + tt) * Hh;
            int i00 = (base + y0) * Ww + x0;
            int i01 = (base + y0) * Ww + x1;
            int i10 = (base + y1) * Ww + x0;
            int i11 = (base + y1) * Ww + x1;
            float c00 = wts * w00 * (mask[i00] ? 0.f : 1.f);
            float c01 = wts * w01 * (mask[i01] ? 0.f : 1.f);
            float c10 = wts * w10 * (mask[i10] ? 0.f : 1.f);
            float c11 = wts * w11 * (mask[i11] ? 0.f : 1.f);
            float4 v00 = f4[(size_t)i00 * 64 + l];
            float4 v01 = f4[(size_t)i01 * 64 + l];
            float4 v10 = f4[(size_t)i10 * 64 + l];
            float4 v11 = f4[(size_t)i11 * 64 + l];
            acc.x += c00 * v00.x + c01 * v01.x + c10 * v10.x + c11 * v11.x;
            acc.y += c00 * v00.y + c01 * v01.y + c10 * v10.y + c11 * v11.y;
            acc.z += c00 * v00.z + c01 * v01.z + c10 * v10.z + c11 * v11.z;
            acc.w += c00 * v00.w + c01 * v01.w + c10 * v10.w + c11 * v11.w;
        }
    }
    ((float4*)&part[j][0])[l] = acc;
    __syncthreads();
    agg[(size_t)bq * Dd + t] = part[0][t] + part[1][t] + part[2][t] + part[3][t];
}

// ---------------- kernel 3: proj + residual + LN2 + FFN (+residual) ----------------
// 4 rows/block, 1024 threads (16 waves). thread t: c = t&255 (col), j = t>>8 (row / K-quarter)
__global__ void __launch_bounds__(1024) k_out(const float* __restrict__ q,
                                              const float* __restrict__ agg,
                                              const float* __restrict__ w_proj,
                                              const float* __restrict__ b_proj,
                                              const float* __restrict__ g2,
                                              const float* __restrict__ b2,
                                              const float* __restrict__ w_ffn1,
                                              const float* __restrict__ b_ffn1,
                                              const float* __restrict__ w_ffn2,
                                              const float* __restrict__ b_ffn2,
                                              float* __restrict__ out) {
    __shared__ float sA[4][256];
    __shared__ float sO[4][256];
    __shared__ float sH[4][256];
    __shared__ float sF[4][1024];
    __shared__ float sP[4][4][256];   // [K-quarter][row][col]
    __shared__ float red[4][4];       // [row][wave-in-group]
    int t = threadIdx.x;
    int c = t & 255, j = t >> 8;
    int row0 = blockIdx.x * 4;

    sA[j][c] = agg[(size_t)(row0 + j) * Dd + c];
    __syncthreads();

    // ---- proj, split-K (quarter j = 64 k's), all 4 rows ----
    {
        float a0 = 0, a1 = 0, a2 = 0, a3 = 0;
        const float4* ar0 = (const float4*)&sA[0][j * 64];
        const float4* ar1 = (const float4*)&sA[1][j * 64];
        const float4* ar2 = (const float4*)&sA[2][j * 64];
        const float4* ar3 = (const float4*)&sA[3][j * 64];
        for (int k4 = 0; k4 < 16; k4++) {
            int k = j * 64 + k4 * 4;
            float w0 = w_proj[(k + 0) * Dd + c];
            float w1 = w_proj[(k + 1) * Dd + c];
            float w2 = w_proj[(k + 2) * Dd + c];
            float w3 = w_proj[(k + 3) * Dd + c];
            float4 h0 = ar0[k4], h1 = ar1[k4], h2 = ar2[k4], h3 = ar3[k4];
            a0 += h0.x * w0 + h0.y * w1 + h0.z * w2 + h0.w * w3;
            a1 += h1.x * w0 + h1.y * w1 + h1.z * w2 + h1.w * w3;
            a2 += h2.x * w0 + h2.y * w1 + h2.z * w2 + h2.w * w3;
            a3 += h3.x * w0 + h3.y * w1 + h3.z * w2 + h3.w * w3;
        }
        sP[j][0][c] = a0; sP[j][1][c] = a1; sP[j][2][c] = a2; sP[j][3][c] = a3;
    }
    __syncthreads();

    // ---- combine partials + residual; LN2 over row j (4 waves per row) ----
    float o = sP[0][j][c] + sP[1][j][c] + sP[2][j][c] + sP[3][j][c]
            + q[(size_t)(row0 + j) * Dd + c] + b_proj[c];
    sO[j][c] = o;
    int wg = (t >> 6) & 3, lane = t & 63;
    float s = wave_reduce(o);
    if (lane == 0) red[j][wg] = s;
    __syncthreads();
    float mean = (red[j][0] + red[j][1] + red[j][2] + red[j][3]) * (1.f / 256.f);
    float dx = o - mean;
    float s2 = wave_reduce(dx * dx);
    __syncthreads();
    if (lane == 0) red[j][wg] = s2;
    __syncthreads();
    float var = (red[j][0] + red[j][1] + red[j][2] + red[j][3]) * (1.f / 256.f);
    float h = dx * rsqrtf(var + 1e-5f) * g2[c] + b2[c];
    sH[j][c] = h;
    __syncthreads();

    // ---- FFN1 + exact GELU: thread t -> col t, all 4 rows ----
    {
        float f0 = 0, f1 = 0, f2 = 0, f3 = 0;
        const float4* h0p = (const float4*)&sH[0][0];
        const float4* h1p = (const float4*)&sH[1][0];
        const float4* h2p = (const float4*)&sH[2][0];
        const float4* h3p = (const float4*)&sH[3][0];
        for (int k4 = 0; k4 < 64; k4++) {
            int k = k4 * 4;
            float w0 = w_ffn1[(size_t)(k + 0) * 1024 + t];
            float w1 = w_ffn1[(size_t)(k + 1) * 1024 + t];
            float w2 = w_ffn1[(size_t)(k + 2) * 1024 + t];
            float w3 = w_ffn1[(size_t)(k + 3) * 1024 + t];
            float4 h0 = h0p[k4], h1 = h1p[k4], h2 = h2p[k4], h3 = h3p[k4];
            f0 += h0.x * w0 + h0.y * w1 + h0.z * w2 + h0.w * w3;
            f1 += h1.x * w0 + h1.y * w1 + h1.z * w2 + h1.w * w3;
            f2 += h2.x * w0 + h2.y * w1 + h2.z * w2 + h2.w * w3;
            f3 += h3.x * w0 + h3.y * w1 + h3.z * w2 + h3.w * w3;
        }
        float bf = b_ffn1[t];
        float v0 = f0 + bf, v1 = f1 + bf, v2 = f2 + bf, v3 = f3 + bf;
        sF[0][t] = 0.5f * v0 * (1.f + erff(v0 * 0.70710678118654752f));
        sF[1][t] = 0.5f * v1 * (1.f + erff(v1 * 0.70710678118654752f));
        sF[2][t] = 0.5f * v2 * (1.f + erff(v2 * 0.70710678118654752f));
        sF[3][t] = 0.5f * v3 * (1.f + erff(v3 * 0.70710678118654752f));
    }
    __syncthreads();

    // ---- FFN2, split-K (quarter j = 256 k's), all 4 rows ----
    {
        float a0 = 0, a1 = 0, a2 = 0, a3 = 0;
        const float4* f0p = (const float4*)&sF[0][j * 256];
        const float4* f1p = (const float4*)&sF[1][j * 256];
        const float4* f2p = (const float4*)&sF[2][j * 256];
        const float4* f3p = (const float4*)&sF[3][j * 256];
        for (int k4 = 0; k4 < 64; k4++) {
            int k = j * 256 + k4 * 4;
            float w0 = w_ffn2[(size_t)(k + 0) * Dd + c];
            float w1 = w_ffn2[(size_t)(k + 1) * Dd + c];
            float w2 = w_ffn2[(size_t)(k + 2) * Dd + c];
            float w3 = w_ffn2[(size_t)(k + 3) * Dd + c];
            float4 h0 = f0p[k4], h1 = f1p[k4], h2 = f2p[k4], h3 = f3p[k4];
            a0 += h0.x * w0 + h0.y * w1 + h0.z * w2 + h0.w * w3;
            a1 += h1.x * w0 + h1.y * w1 + h1.z * w2 + h1.w * w3;
            a2 += h2.x * w0 + h2.y * w1 + h2.z * w2 + h2.w * w3;
            a3 += h3.x * w0 + h3.y * w1 + h3.z * w2 + h3.w * w3;
        }
        sP[j][0][c] = a0; sP[j][1][c] = a1; sP[j][2][c] = a2; sP[j][3][c] = a3;
    }
    __syncthreads();

    float r2 = sP[0][j][c] + sP[1][j][c] + sP[2][j][c] + sP[3][j][c];
    out[(size_t)(row0 + j) * Dd + c] = sO[j][c] + r2 + b_ffn2[c];
}

// ---------------- launcher ----------------
extern "C" void kernel_launch(void* const* d_in, const int* in_sizes, int n_in,
                              void* d_out, int out_size, void* d_ws, size_t ws_size,
                              hipStream_t stream) {
    const float* q        = (const float*)d_in[0];
    const float* kv_feats = (const float*)d_in[1];
    const unsigned char* kv_mask = (const unsigned char*)d_in[2];
    const float* delta_sec= (const float*)d_in[3];
    const float* w_ref    = (const float*)d_in[4];
    const float* b_ref    = (const float*)d_in[5];
    const float* w_delta  = (const float*)d_in[6];
    const float* b_delta  = (const float*)d_in[7];
    const float* w_alpha  = (const float*)d_in[8];
    const float* b_alpha  = (const float*)d_in[9];
    // d_in[10] = lam: softmax shift-invariance makes it a no-op
    const float* w_proj   = (const float*)d_in[11];
    const float* b_proj   = (const float*)d_in[12];
    const float* ln1_g    = (const float*)d_in[13];
    const float* ln1_b    = (const float*)d_in[14];
    const float* ln2_g    = (const float*)d_in[15];
    const float* ln2_b    = (const float*)d_in[16];
    const float* w_ffn1   = (const float*)d_in[17];
    const float* b_ffn1   = (const float*)d_in[18];
    const float* w_ffn2   = (const float*)d_in[19];
    const float* b_ffn2   = (const float*)d_in[20];
    const float* w_rel    = (const float*)d_in[21];
    const float* b_rel    = (const float*)d_in[22];
    float* out = (float*)d_out;

    float* ws  = (float*)d_ws;
    float* prm = ws;                       // 1200*32*12 = 460800 floats
    float* agg = ws + 460800;              // 1200*256  = 307200 floats

    const int BQ = Bn * Qn;                // 1200
    k_pts<<<dim3(BQ), dim3(256), 0, stream>>>(q, ln1_g, ln1_b, w_ref, b_ref, delta_sec,
                                              w_rel, b_rel, w_delta, b_delta,
                                              w_alpha, b_alpha, prm);
    k_sample<<<dim3(BQ), dim3(256), 0, stream>>>(kv_feats, kv_mask, prm, agg);
    k_out<<<dim3(BQ / 4), dim3(1024), 0, stream>>>(q, agg, w_proj, b_proj, ln2_g, ln2_b,
                                                   w_ffn1, b_ffn1, w_ffn2, b_ffn2, out);
}

// Round 4
// 307.870 us; speedup vs baseline: 1.3604x; 1.1293x over previous
//
#include <hip/hip_runtime.h>
#include <math.h>

#define Bn 4
#define Qn 300
#define WL 8
#define Hh 64
#define Ww 64
#define Dd 256
#define Mm 4

// ---------------- helpers ----------------
__device__ __forceinline__ float wave_reduce(float v) {
#pragma unroll
    for (int off = 32; off > 0; off >>= 1) v += __shfl_down(v, off, 64);
    return v;
}

__device__ __forceinline__ float block_reduce256(float v, float* lds) {
    v = wave_reduce(v);
    int lane = threadIdx.x & 63, wv = threadIdx.x >> 6;
    if (lane == 0) lds[wv] = v;
    __syncthreads();
    float r = lds[0] + lds[1] + lds[2] + lds[3];
    __syncthreads();
    return r;
}

__device__ __forceinline__ float lo16(unsigned u) { return __uint_as_float(u << 16); }
__device__ __forceinline__ float hi16(unsigned u) { return __uint_as_float(u & 0xffff0000u); }

__device__ __forceinline__ unsigned bfp(float a, float b) {
    unsigned ua = __float_as_uint(a); ua = (ua + 0x7fffu + ((ua >> 16) & 1u)) >> 16;
    unsigned ub = __float_as_uint(b); ub = (ub + 0x7fffu + ((ub >> 16) & 1u)) >> 16;
    return ua | (ub << 16);
}

// ---------------- kernel 0: pack weights to bf16 pairs ----------------
__global__ void __launch_bounds__(256) k_pack(const float* __restrict__ wp,
                                              const float* __restrict__ wf1,
                                              const float* __restrict__ wf2,
                                              unsigned* __restrict__ pk) {
    int i = blockIdx.x * 256 + threadIdx.x;   // 0..294911
    if (i < 32768) {
        int kk = i >> 8, c = i & 255;
        pk[i] = bfp(wp[(2 * kk) * 256 + c], wp[(2 * kk + 1) * 256 + c]);
    } else if (i < 163840) {
        int i2 = i - 32768; int kk = i2 >> 10, c = i2 & 1023;
        pk[i] = bfp(wf1[(2 * kk) * 1024 + c], wf1[(2 * kk + 1) * 1024 + c]);
    } else {
        int i3 = i - 163840; int kk = i3 >> 8, c = i3 & 255;
        pk[i] = bfp(wf2[(2 * kk) * 256 + c], wf2[(2 * kk + 1) * 256 + c]);
    }
}

// ---------------- kernel 1: LN1 + point params + mask-folded gather records ----------------
// record per (b,q,wl,m) = 16 uints: [0..7] corner weights (f32 bits), [8..15] cell indices
__global__ void __launch_bounds__(256) k_mid(const float* __restrict__ q,
                                             const float* __restrict__ g1,
                                             const float* __restrict__ b1,
                                             const float* __restrict__ w_ref,
                                             const float* __restrict__ b_ref,
                                             const float* __restrict__ dsec,
                                             const float* __restrict__ w_rel,
                                             const float* __restrict__ b_rel,
                                             const float* __restrict__ w_delta,
                                             const float* __restrict__ b_delta,
                                             const float* __restrict__ w_alpha,
                                             const float* __restrict__ b_alpha,
                                             const unsigned char* __restrict__ mask,
                                             unsigned* __restrict__ prm2) {
    __shared__ float lds[4];
    __shared__ float sref[2];
    __shared__ float sqn[256];
    __shared__ float pe[8][64];
    __shared__ float rel[8][260];     // +4 pad: 16B-aligned float4 rows
    __shared__ float WcT[16 * 516];   // WcT[j][k], row stride 516
    __shared__ float res[8][16];

    int bq = blockIdx.x, t = threadIdx.x;

    // ---- LN1 ----
    float x = q[bq * Dd + t];
    float m = block_reduce256(x, lds) * (1.f / Dd);
    float dx = x - m;
    float v = block_reduce256(dx * dx, lds) * (1.f / Dd);
    float y = dx * rsqrtf(v + 1e-5f) * g1[t] + b1[t];
    sqn[t] = y;

    // ---- ref = sigmoid(qn @ w_ref + b_ref) ----
    float s0 = block_reduce256(y * w_ref[t * 2 + 0], lds);
    float s1 = block_reduce256(y * w_ref[t * 2 + 1], lds);
    if (t == 0) {
        sref[0] = 1.f / (1.f + expf(-(s0 + b_ref[0])));
        sref[1] = 1.f / (1.f + expf(-(s1 + b_ref[1])));
    }

    // ---- sinusoidal PE for all 8 windows ----
    {
        int wl = t >> 5, i = t & 31;
        float f = expf(-logf(10000.f) * (float)i * (1.f / 32.f));
        float a = dsec[bq * WL + wl] * f;
        pe[wl][i] = sinf(a);
        pe[wl][i + 32] = cosf(a);
    }

    // ---- stage combined delta/alpha weights into LDS (transposed) ----
    for (int u = t; u < 512 * 16; u += 256) {
        int k = u >> 4, jj = u & 15;
        float w = (jj < 12) ? w_delta[k * 12 + jj] : w_alpha[k * 4 + (jj - 12)];
        WcT[jj * 516 + k] = w;
    }

    // ---- w_rel column t in registers ----
    float wr[64];
#pragma unroll
    for (int k = 0; k < 64; k++) wr[k] = w_rel[k * Dd + t];
    __syncthreads();

    // ---- rel_feat per window (pe via float4 broadcast reads) ----
    float brl = b_rel[t];
    for (int wl = 0; wl < WL; wl++) {
        const float4* p4 = (const float4*)&pe[wl][0];
        float r = brl;
#pragma unroll
        for (int k4 = 0; k4 < 16; k4++) {
            float4 p = p4[k4];
            r += p.x * wr[4 * k4] + p.y * wr[4 * k4 + 1]
               + p.z * wr[4 * k4 + 2] + p.w * wr[4 * k4 + 3];
        }
        rel[wl][t] = r;
    }
    __syncthreads();

    // ---- 16 dot products per window ----
    if (t < 128) {
        int wl = t >> 4, jj = t & 15;
        const float4* wrow = (const float4*)&WcT[jj * 516];
        const float4* qrow = (const float4*)sqn;
        const float4* rrow = (const float4*)&rel[wl][0];
        float s = 0.f;
#pragma unroll 8
        for (int k4 = 0; k4 < 64; k4++) {
            float4 a = qrow[k4], w = wrow[k4];
            s += a.x * w.x + a.y * w.y + a.z * w.z + a.w * w.w;
        }
#pragma unroll 8
        for (int k4 = 0; k4 < 64; k4++) {
            float4 a = rrow[k4], w = wrow[64 + k4];
            s += a.x * w.x + a.y * w.y + a.z * w.z + a.w * w.w;
        }
        s += (jj < 12) ? b_delta[jj] : b_alpha[jj - 12];
        res[wl][jj] = s;
    }
    __syncthreads();

    // ---- per-point records ----
    if (t < 32) {
        int wl = t >> 2, mm = t & 3;
        float l0 = res[wl][12], l1 = res[wl][13], l2 = res[wl][14], l3 = res[wl][15];
        float mx = fmaxf(fmaxf(l0, l1), fmaxf(l2, l3));
        float inv = 1.f / (expf(l0 - mx) + expf(l1 - mx) + expf(l2 - mx) + expf(l3 - mx));
        // -lam_sp*|dsec| shift is constant across M -> drops out of softmax
        float wgt = expf(res[wl][12 + mm] - mx) * inv;

        float cx = fminf(fmaxf(sref[0] + tanhf(res[wl][mm * 3 + 0]), 0.f), 1.f);
        float cy = fminf(fmaxf(sref[1] + tanhf(res[wl][mm * 3 + 1]), 0.f), 1.f);
        float tgt = (float)wl + tanhf(res[wl][mm * 3 + 2]);
        float t0f = fminf(fmaxf(floorf(tgt), 0.f), (float)(WL - 1));
        float t1f = fminf(t0f + 1.f, (float)(WL - 1));
        float alpha = tgt - t0f;
        float px = cx * (float)Ww - 0.5f, py = cy * (float)Hh - 0.5f;
        float fx = floorf(px), fy = floorf(py);
        float wx = px - fx, wy = py - fy;
        int X0 = (int)fminf(fmaxf(fx, 0.f), (float)(Ww - 1));
        int X1 = (int)fminf(fmaxf(fx + 1.f, 0.f), (float)(Ww - 1));
        int Y0 = (int)fminf(fmaxf(fy, 0.f), (float)(Hh - 1));
        int Y1 = (int)fminf(fmaxf(fy + 1.f, 0.f), (float)(Hh - 1));
        int T0 = (int)t0f, T1 = (int)t1f;

        float w00 = (1.f - wy) * (1.f - wx), w01 = (1.f - wy) * wx;
        float w10 = wy * (1.f - wx), w11 = wy * wx;
        float wt0 = wgt * (1.f - alpha), wt1 = wgt * alpha;

        int b = bq / Qn;
        int base0 = (b * WL + T0) * Hh;
        int base1 = (b * WL + T1) * Hh;
        int i00 = (base0 + Y0) * Ww + X0, i01 = (base0 + Y0) * Ww + X1;
        int i10 = (base0 + Y1) * Ww + X0, i11 = (base0 + Y1) * Ww + X1;
        int j00 = (base1 + Y0) * Ww + X0, j01 = (base1 + Y0) * Ww + X1;
        int j10 = (base1 + Y1) * Ww + X0, j11 = (base1 + Y1) * Ww + X1;

        unsigned* rec = prm2 + (unsigned)(bq * 32 + t) * 16;
        rec[0] = __float_as_uint(wt0 * w00 * (mask[i00] ? 0.f : 1.f));
        rec[1] = __float_as_uint(wt0 * w01 * (mask[i01] ? 0.f : 1.f));
        rec[2] = __float_as_uint(wt0 * w10 * (mask[i10] ? 0.f : 1.f));
        rec[3] = __float_as_uint(wt0 * w11 * (mask[i11] ? 0.f : 1.f));
        rec[4] = __float_as_uint(wt1 * w00 * (mask[j00] ? 0.f : 1.f));
        rec[5] = __float_as_uint(wt1 * w01 * (mask[j01] ? 0.f : 1.f));
        rec[6] = __float_as_uint(wt1 * w10 * (mask[j10] ? 0.f : 1.f));
        rec[7] = __float_as_uint(wt1 * w11 * (mask[j11] ? 0.f : 1.f));
        rec[8] = i00; rec[9] = i01; rec[10] = i10; rec[11] = i11;
        rec[12] = j00; rec[13] = j01; rec[14] = j10; rec[15] = j11;
    }
}

// ---------------- kernel 2: gather + weighted aggregation ----------------
__global__ void __launch_bounds__(512) k_gather(const float* __restrict__ feats,
                                                const unsigned* __restrict__ prm2,
                                                float* __restrict__ agg) {
    __shared__ unsigned P[32 * 16];
    __shared__ float part[8][256];
    int bq = blockIdx.x, t = threadIdx.x;
    int l = t & 63, j = t >> 6;
    P[t] = prm2[(unsigned)bq * 512 + t];
    __syncthreads();
    const float4* f4 = (const float4*)feats;
    float4 acc = {0.f, 0.f, 0.f, 0.f};
#pragma unroll
    for (int p = 0; p < 4; p++) {
        const unsigned* rec = &P[(j * 4 + p) * 16];
#pragma unroll
        for (int cn = 0; cn < 8; cn++) {
            float w = __uint_as_float(rec[cn]);
            size_t idx = rec[8 + cn];
            float4 v = f4[idx * 64 + l];
            acc.x += w * v.x; acc.y += w * v.y; acc.z += w * v.z; acc.w += w * v.w;
        }
    }
    ((float4*)&part[j][0])[l] = acc;
    __syncthreads();
    if (t < 256) {
        float s = part[0][t] + part[1][t] + part[2][t] + part[3][t]
                + part[4][t] + part[5][t] + part[6][t] + part[7][t];
        agg[(size_t)bq * Dd + t] = s;
    }
}

// ---------------- kernel 3: proj + residual + LN2 + FFN (+residual) ----------------
template<int R>
__device__ __forceinline__ void out_body(int row0,
        const float* __restrict__ q, const float* __restrict__ agg,
        const unsigned* __restrict__ pkP, const float* __restrict__ b_proj,
        const float* __restrict__ g2, const float* __restrict__ b2,
        const unsigned* __restrict__ pkF1, const float* __restrict__ b_ffn1,
        const unsigned* __restrict__ pkF2, const float* __restrict__ b_ffn2,
        float* __restrict__ out,
        float* sA, float* sO, float* sH, float* sF, float* sP, float* sRed) {
    int t = threadIdx.x;
    int c = t & 255, j = t >> 8;

    for (int u = t; u < 256 * R; u += 1024) {
        int r = u >> 8, cc = u & 255;
        sA[r * 256 + cc] = agg[(size_t)(row0 + r) * Dd + cc];
    }
    __syncthreads();

    // ---- proj, split-K quarter j (64 k's = 32 pairs) ----
    {
        float acc[R];
#pragma unroll
        for (int r = 0; r < R; r++) acc[r] = 0.f;
        const unsigned* wp = pkP + (j * 32) * 256 + c;
#pragma unroll 4
        for (int q4 = 0; q4 < 16; q4++) {
            unsigned u0 = wp[(2 * q4) * 256];
            unsigned u1 = wp[(2 * q4 + 1) * 256];
            float w0 = lo16(u0), w1 = hi16(u0), w2 = lo16(u1), w3 = hi16(u1);
#pragma unroll
            for (int r = 0; r < R; r++) {
                float4 a = ((const float4*)&sA[r * 256 + j * 64])[q4];
                acc[r] += a.x * w0 + a.y * w1 + a.z * w2 + a.w * w3;
            }
        }
#pragma unroll
        for (int r = 0; r < R; r++) sP[(j * 5 + r) * 256 + c] = acc[r];
    }
    __syncthreads();

    // ---- combine + residual ----
    for (int u = t; u < 256 * R; u += 1024) {
        int r = u >> 8, cc = u & 255;
        float o = sP[(0 * 5 + r) * 256 + cc] + sP[(1 * 5 + r) * 256 + cc]
                + sP[(2 * 5 + r) * 256 + cc] + sP[(3 * 5 + r) * 256 + cc]
                + q[(size_t)(row0 + r) * Dd + cc] + b_proj[cc];
        sO[r * 256 + cc] = o;
    }
    __syncthreads();

    // ---- LN2: wave r reduces row r ----
    {
        int wv = t >> 6, l = t & 63;
        if (wv < R) {
            float4 v = ((const float4*)&sO[wv * 256])[l];
            float s = v.x + v.y + v.z + v.w;
            s = __shfl(wave_reduce(s), 0, 64);
            float mean = s * (1.f / 256.f);
            float d0 = v.x - mean, d1 = v.y - mean, d2 = v.z - mean, d3 = v.w - mean;
            float ss = d0 * d0 + d1 * d1 + d2 * d2 + d3 * d3;
            ss = __shfl(wave_reduce(ss), 0, 64);
            float rstd = rsqrtf(ss * (1.f / 256.f) + 1e-5f);
            if (l == 0) { sRed[wv * 2] = mean; sRed[wv * 2 + 1] = rstd; }
        }
    }
    __syncthreads();
    for (int u = t; u < 256 * R; u += 1024) {
        int r = u >> 8, cc = u & 255;
        sH[r * 256 + cc] = (sO[r * 256 + cc] - sRed[r * 2]) * sRed[r * 2 + 1] * g2[cc] + b2[cc];
    }
    __syncthreads();

    // ---- FFN1 + exact GELU: thread t = col; K=256 -> 64 iters x 4 k (128 pairs) ----
    {
        float f[R];
#pragma unroll
        for (int r = 0; r < R; r++) f[r] = 0.f;
        const unsigned* wp = pkF1 + t;
#pragma unroll 4
        for (int q4 = 0; q4 < 64; q4++) {          // FIX: was 32 (dropped half of K)
            unsigned u0 = wp[(2 * q4) * 1024];
            unsigned u1 = wp[(2 * q4 + 1) * 1024];
            float w0 = lo16(u0), w1 = hi16(u0), w2 = lo16(u1), w3 = hi16(u1);
#pragma unroll
            for (int r = 0; r < R; r++) {
                float4 h = ((const float4*)&sH[r * 256])[q4];
                f[r] += h.x * w0 + h.y * w1 + h.z * w2 + h.w * w3;
            }
        }
        float bf = b_ffn1[t];
#pragma unroll
        for (int r = 0; r < R; r++) {
            float xx = f[r] + bf;
            sF[r * 1024 + t] = 0.5f * xx * (1.f + erff(xx * 0.70710678118654752f));
        }
    }
    __syncthreads();

    // ---- FFN2, split-K quarter j (256 k's = 128 pairs) ----
    {
        float acc[R];
#pragma unroll
        for (int r = 0; r < R; r++) acc[r] = 0.f;
        const unsigned* wp = pkF2 + (j * 128) * 256 + c;
#pragma unroll 4
        for (int q4 = 0; q4 < 64; q4++) {
            unsigned u0 = wp[(2 * q4) * 256];
            unsigned u1 = wp[(2 * q4 + 1) * 256];
            float w0 = lo16(u0), w1 = hi16(u0), w2 = lo16(u1), w3 = hi16(u1);
#pragma unroll
            for (int r = 0; r < R; r++) {
                float4 h = ((const float4*)&sF[r * 1024 + j * 256])[q4];
                acc[r] += h.x * w0 + h.y * w1 + h.z * w2 + h.w * w3;
            }
        }
#pragma unroll
        for (int r = 0; r < R; r++) sP[(j * 5 + r) * 256 + c] = acc[r];
    }
    __syncthreads();

    for (int u = t; u < 256 * R; u += 1024) {
        int r = u >> 8, cc = u & 255;
        float s = sP[(0 * 5 + r) * 256 + cc] + sP[(1 * 5 + r) * 256 + cc]
                + sP[(2 * 5 + r) * 256 + cc] + sP[(3 * 5 + r) * 256 + cc];
        out[(size_t)(row0 + r) * Dd + cc] = sO[r * 256 + cc] + s + b_ffn2[cc];
    }
}

__global__ void __launch_bounds__(1024) k_out(const float* __restrict__ q,
                                              const float* __restrict__ agg,
                                              const unsigned* __restrict__ pkP,
                                              const float* __restrict__ b_proj,
                                              const float* __restrict__ g2,
                                              const float* __restrict__ b2,
                                              const unsigned* __restrict__ pkF1,
                                              const float* __restrict__ b_ffn1,
                                              const unsigned* __restrict__ pkF2,
                                              const float* __restrict__ b_ffn2,
                                              float* __restrict__ out) {
    __shared__ float sA[5 * 256];
    __shared__ float sO[5 * 256];
    __shared__ float sH[5 * 256];
    __shared__ float sF[5 * 1024];
    __shared__ float sP[4 * 5 * 256];
    __shared__ float sRed[16];
    __shared__ float pad[8192];   // inflate LDS -> exactly 1 block/CU (perfect balance)
    if (b_ffn2 == nullptr) pad[threadIdx.x] = 0.f;   // keeps pad alive; never executes

    int bid = blockIdx.x;
    if (bid < 176) {
        out_body<5>(bid * 5, q, agg, pkP, b_proj, g2, b2, pkF1, b_ffn1, pkF2, b_ffn2,
                    out, sA, sO, sH, sF, sP, sRed);
    } else {
        out_body<4>(880 + (bid - 176) * 4, q, agg, pkP, b_proj, g2, b2, pkF1, b_ffn1,
                    pkF2, b_ffn2, out, sA, sO, sH, sF, sP, sRed);
    }
}

// ---------------- launcher ----------------
extern "C" void kernel_launch(void* const* d_in, const int* in_sizes, int n_in,
                              void* d_out, int out_size, void* d_ws, size_t ws_size,
                              hipStream_t stream) {
    const float* q        = (const float*)d_in[0];
    const float* kv_feats = (const float*)d_in[1];
    const unsigned char* kv_mask = (const unsigned char*)d_in[2];
    const float* delta_sec= (const float*)d_in[3];
    const float* w_ref    = (const float*)d_in[4];
    const float* b_ref    = (const float*)d_in[5];
    const float* w_delta  = (const float*)d_in[6];
    const float* b_delta  = (const float*)d_in[7];
    const float* w_alpha  = (const float*)d_in[8];
    const float* b_alpha  = (const float*)d_in[9];
    // d_in[10] = lam: softmax shift-invariance makes it a no-op
    const float* w_proj   = (const float*)d_in[11];
    const float* b_proj   = (const float*)d_in[12];
    const float* ln1_g    = (const float*)d_in[13];
    const float* ln1_b    = (const float*)d_in[14];
    const float* ln2_g    = (const float*)d_in[15];
    const float* ln2_b    = (const float*)d_in[16];
    const float* w_ffn1   = (const float*)d_in[17];
    const float* b_ffn1   = (const float*)d_in[18];
    const float* w_ffn2   = (const float*)d_in[19];
    const float* b_ffn2   = (const float*)d_in[20];
    const float* w_rel    = (const float*)d_in[21];
    const float* b_rel    = (const float*)d_in[22];
    float* out = (float*)d_out;

    unsigned* pk   = (unsigned*)d_ws;          // 294912 uints (pkP|pkF1|pkF2)
    unsigned* pkP  = pk;
    unsigned* pkF1 = pk + 32768;
    unsigned* pkF2 = pk + 163840;
    unsigned* prm2 = pk + 294912;              // 1200*32*16 = 614400 uints
    float*    agg  = (float*)(pk + 294912 + 614400);   // 1200*256 floats

    const int BQ = Bn * Qn;                    // 1200
    k_pack<<<dim3(1152), dim3(256), 0, stream>>>(w_proj, w_ffn1, w_ffn2, pk);
    k_mid<<<dim3(BQ), dim3(256), 0, stream>>>(q, ln1_g, ln1_b, w_ref, b_ref, delta_sec,
                                              w_rel, b_rel, w_delta, b_delta,
                                              w_alpha, b_alpha, kv_mask, prm2);
    k_gather<<<dim3(BQ), dim3(512), 0, stream>>>(kv_feats, prm2, agg);
    k_out<<<dim3(256), dim3(1024), 0, stream>>>(q, agg, pkP, b_proj, ln2_g, ln2_b,
                                                pkF1, b_ffn1, pkF2, b_ffn2, out);
}